// Round 3
// baseline (161.364 us; speedup 1.0000x reference)
//
#include <hip/hip_runtime.h>

// Output of reference = haar_wavedec(x, 3) only; the MLP (psi) is dead code.
// x: (B=128, C=128, L=1024) fp32. Rows = B*C = 16384, each of length L=1024.
// Out layout (flat): a3[NR][128], d3[NR][128], d2[NR][256], d1[NR][512].
// One thread per 16 consecutive input elements (two independent 8-groups):
// loads 4x float4 (64B/lane), stores 2x float4 (d1) + float4 (d2) + float2 (d3)
// + float2 (a3) — every store stream >= 8B/lane, all coalesced.

constexpr int L = 1024;
constexpr int TPR = L / 16;          // threads per row = 64
constexpr float C_INV_SQRT2 = 0.7071067811865476f;

__global__ __launch_bounds__(256) void haar3_kernel(const float* __restrict__ x,
                                                    float* __restrict__ out,
                                                    int n_rows) {
    const int t = blockIdx.x * blockDim.x + threadIdx.x;
    const int total = n_rows * TPR;
    if (t >= total) return;

    const float c = C_INV_SQRT2;
    const float4* xv = reinterpret_cast<const float4*>(x) + 4 * (size_t)t;
    const float4 v0 = xv[0];
    const float4 v1 = xv[1];
    const float4 v2 = xv[2];
    const float4 v3 = xv[3];

    // Level 1: (e +/- o) * c  — same association order as reference.
    const float a10 = (v0.x + v0.y) * c, a11 = (v0.z + v0.w) * c;
    const float a12 = (v1.x + v1.y) * c, a13 = (v1.z + v1.w) * c;
    const float a14 = (v2.x + v2.y) * c, a15 = (v2.z + v2.w) * c;
    const float a16 = (v3.x + v3.y) * c, a17 = (v3.z + v3.w) * c;
    float4 d1a, d1b;
    d1a.x = (v0.x - v0.y) * c; d1a.y = (v0.z - v0.w) * c;
    d1a.z = (v1.x - v1.y) * c; d1a.w = (v1.z - v1.w) * c;
    d1b.x = (v2.x - v2.y) * c; d1b.y = (v2.z - v2.w) * c;
    d1b.z = (v3.x - v3.y) * c; d1b.w = (v3.z - v3.w) * c;

    // Level 2
    const float a20 = (a10 + a11) * c, a21 = (a12 + a13) * c;
    const float a22 = (a14 + a15) * c, a23 = (a16 + a17) * c;
    float4 d2v;
    d2v.x = (a10 - a11) * c; d2v.y = (a12 - a13) * c;
    d2v.z = (a14 - a15) * c; d2v.w = (a16 - a17) * c;

    // Level 3
    float2 a3v, d3v;
    a3v.x = (a20 + a21) * c; a3v.y = (a22 + a23) * c;
    d3v.x = (a20 - a21) * c; d3v.y = (a22 - a23) * c;

    const size_t NR = (size_t)n_rows;
    const size_t base = NR * (size_t)TPR;   // 1M elems per "128-wide" region unit
    // a3 region [0, NR*128):  thread covers a3[r][2k..2k+2) -> float2 index t.
    reinterpret_cast<float2*>(out)[t] = a3v;
    // d3 region at +NR*128, float2 index t.
    reinterpret_cast<float2*>(out + base * 2)[t] = d3v;
    // d2 region at +NR*256, thread covers d2[r][4k..4k+4) -> float4 index t.
    reinterpret_cast<float4*>(out + base * 4)[t] = d2v;
    // d1 region at +NR*512, thread covers d1[r][8k..8k+8) -> float4 idx 2t, 2t+1.
    float4* d1p = reinterpret_cast<float4*>(out + base * 8) + 2 * (size_t)t;
    d1p[0] = d1a;
    d1p[1] = d1b;
}

extern "C" void kernel_launch(void* const* d_in, const int* in_sizes, int n_in,
                              void* d_out, int out_size, void* d_ws, size_t ws_size,
                              hipStream_t stream) {
    const float* x = (const float*)d_in[0];
    float* out = (float*)d_out;
    const int n_rows = in_sizes[0] / L;          // 16384
    const int total_threads = n_rows * TPR;      // 1,048,576
    const int block = 256;
    const int grid = (total_threads + block - 1) / block;  // 4096
    haar3_kernel<<<grid, block, 0, stream>>>(x, out, n_rows);
}